// Round 7
// baseline (190.789 us; speedup 1.0000x reference)
//
#include <hip/hip_runtime.h>

#define BATCH 32
#define H 512
#define W 512
#define SEG 8                       // output rows per block
#define TPB 64                      // ONE wave per block: no barriers anywhere
// final scalar = sum over pixels of ((1-cc1)+(1-cc2)) * 0.5 / (B*H*W)
#define SCALE (0.5f / 8388608.0f)

typedef float f32x4 __attribute__((ext_vector_type(4)));

__global__ __launch_bounds__(TPB) void ncc_loss_kernel(
    const float* __restrict__ g1, const float* __restrict__ g2,
    const float* __restrict__ gf, float* __restrict__ out)
{
    const int lane = threadIdx.x;                    // owns 4 cols of a 256-col tile
    const int voff = blockIdx.x * 1024 + 16 * lane;  // byte offset of own x4 in row
    const int y0   = blockIdx.y * SEG;
    const int b    = blockIdx.z;
    const size_t base = (size_t)b * (H * W);

    const bool e0  = (lane == 0);
    const bool e63 = (lane == TPB - 1);
    // halo-patch offset: lane0 needs [voff-16, lane63 needs voff+16.
    // OOB cases (tile0 lane0: -16 wraps; tile1 lane63: 2048) -> SRD check -> 0.0f
    const int eoff = e0 ? (voff - 16) : (voff + 16);

    // vertical running sums, 8 quantities x 4 columns
    float v1[4], v2[4], vf[4], v11[4], v22[4], vff[4], v1f[4], v2f[4];
#pragma unroll
    for (int c = 0; c < 4; ++c) {
        v1[c]=0.f; v2[c]=0.f; vf[c]=0.f; v11[c]=0.f;
        v22[c]=0.f; vff[c]=0.f; v1f[c]=0.f; v2f[c]=0.f;
    }
    float lsum = 0.f;
    const float inv_n = 1.0f / 81.0f;

    // visit one raw row: 3 own x4 loads + neighbor quarters via shuffle +
    // 1 masked patch-load for the 2 edge lanes. sub=false: enter, true: leave.
    // Leave rows recompute bitwise-identical h-sums -> exact cancellation.
    auto visit = [&](int yr, bool sub) {
        const int rec = ((unsigned)yr < (unsigned)H) ? (W * 4) : 0;  // v-pad
        const int yc  = yr < 0 ? 0 : (yr >= H ? H - 1 : yr);
        const size_t roff = base + (size_t)yc * W;
        __amdgpu_buffer_rsrc_t ra = __builtin_amdgcn_make_buffer_rsrc(
            (void*)(g1 + roff), (short)0, rec, 0x00020000);
        __amdgpu_buffer_rsrc_t rc = __builtin_amdgcn_make_buffer_rsrc(
            (void*)(g2 + roff), (short)0, rec, 0x00020000);
        __amdgpu_buffer_rsrc_t rv = __builtin_amdgcn_make_buffer_rsrc(
            (void*)(gf + roff), (short)0, rec, 0x00020000);

        const f32x4 A1 = __builtin_bit_cast(f32x4,
            __builtin_amdgcn_raw_buffer_load_b128(ra, voff, 0, 0));
        const f32x4 C1 = __builtin_bit_cast(f32x4,
            __builtin_amdgcn_raw_buffer_load_b128(rc, voff, 0, 0));
        const f32x4 F1 = __builtin_bit_cast(f32x4,
            __builtin_amdgcn_raw_buffer_load_b128(rv, voff, 0, 0));

        f32x4 A0, C0, F0, A2, C2, F2;                // left / right quarters
#pragma unroll
        for (int i = 0; i < 4; ++i) {
            A0[i] = __shfl_up(A1[i], 1, 64);
            C0[i] = __shfl_up(C1[i], 1, 64);
            F0[i] = __shfl_up(F1[i], 1, 64);
            A2[i] = __shfl_down(A1[i], 1, 64);
            C2[i] = __shfl_down(C1[i], 1, 64);
            F2[i] = __shfl_down(F1[i], 1, 64);
        }
        if (e0 | e63) {                              // patch the 2 edge lanes
            const f32x4 pa = __builtin_bit_cast(f32x4,
                __builtin_amdgcn_raw_buffer_load_b128(ra, eoff, 0, 0));
            const f32x4 pc = __builtin_bit_cast(f32x4,
                __builtin_amdgcn_raw_buffer_load_b128(rc, eoff, 0, 0));
            const f32x4 pf = __builtin_bit_cast(f32x4,
                __builtin_amdgcn_raw_buffer_load_b128(rv, eoff, 0, 0));
            if (e0) { A0 = pa; C0 = pc; F0 = pf; }
            else    { A2 = pa; C2 = pc; F2 = pf; }
        }

        float wa[12], wc[12], wf[12];                // window cols 4t-4 .. 4t+7
#pragma unroll
        for (int i = 0; i < 4; ++i) {
            wa[i] = A0[i]; wa[4+i] = A1[i]; wa[8+i] = A2[i];
            wc[i] = C0[i]; wc[4+i] = C1[i]; wc[8+i] = C2[i];
            wf[i] = F0[i]; wf[4+i] = F1[i]; wf[8+i] = F2[i];
        }

        // 4 sliding horizontal 9-window sums from 12 values
        auto hwin = [](const float* w, float* h) {
            float s = w[0]+w[1]+w[2]+w[3]+w[4]+w[5]+w[6]+w[7]+w[8];
            h[0]=s; s += w[9]-w[0]; h[1]=s; s += w[10]-w[1]; h[2]=s; s += w[11]-w[2]; h[3]=s;
        };
        auto hwinp = [](const float* u, const float* w, float* h) {
            const float p0=u[0]*w[0], p1=u[1]*w[1], p2=u[2]*w[2];
            float s = p0+p1+p2;
#pragma unroll
            for (int i = 3; i <= 8; ++i) s = fmaf(u[i], w[i], s);
            h[0]=s; s = fmaf(u[9],w[9],s)-p0; h[1]=s;
            s = fmaf(u[10],w[10],s)-p1; h[2]=s;
            s = fmaf(u[11],w[11],s)-p2; h[3]=s;
        };

        float ha[4],hc[4],hf[4],haa[4],hcc[4],hff[4],haf[4],hcf[4];
        hwin(wa,ha); hwin(wc,hc); hwin(wf,hf);
        hwinp(wa,wa,haa); hwinp(wc,wc,hcc); hwinp(wf,wf,hff);
        hwinp(wa,wf,haf); hwinp(wc,wf,hcf);
        const float sg = sub ? -1.0f : 1.0f;
#pragma unroll
        for (int c = 0; c < 4; ++c) {
            v1[c]  = fmaf(sg, ha[c],  v1[c]);
            v2[c]  = fmaf(sg, hc[c],  v2[c]);
            vf[c]  = fmaf(sg, hf[c],  vf[c]);
            v11[c] = fmaf(sg, haa[c], v11[c]);
            v22[c] = fmaf(sg, hcc[c], v22[c]);
            vff[c] = fmaf(sg, hff[c], vff[c]);
            v1f[c] = fmaf(sg, haf[c], v1f[c]);
            v2f[c] = fmaf(sg, hcf[c], v2f[c]);
        }
    };

    auto emit = [&]() {
#pragma unroll
        for (int c = 0; c < 4; ++c) {
            const float u1 = v1[c]*inv_n, u2 = v2[c]*inv_n, uf = vf[c]*inv_n;
            const float cross1 = fmaf(-v1[c], uf, v1f[c]);
            const float var1   = fmaf(-v1[c], u1, v11[c]);
            const float varf   = fmaf(-vf[c], uf, vff[c]);
            const float cross2 = fmaf(-v2[c], uf, v2f[c]);
            const float var2   = fmaf(-v2[c], u2, v22[c]);
            const float d1 = fmaf(var1, varf, 1e-5f);
            const float d2 = fmaf(var2, varf, 1e-5f);
            // cc1 + cc2 = (cross1^2*d2 + cross2^2*d1) / (d1*d2): one rcp
            const float inv = __builtin_amdgcn_rcpf(d1 * d2);
            float num = cross1 * cross1 * d2;
            num = fmaf(cross2 * cross2, d1, num);
            lsum += fmaf(-num, inv, 2.0f);           // (1-cc1)+(1-cc2)
        }
    };

    // prologue: rows y0-4 .. y0+4 -> window for output row y0
#pragma unroll 1
    for (int s = 0; s < 9; ++s) visit(y0 - 4 + s, false);
    emit();
    // steady state: leave oldest row, enter next row, emit
#pragma unroll 1
    for (int j = 1; j < SEG; ++j) {
        visit(y0 - 5 + j, true);
        visit(y0 + 4 + j, false);
        emit();
    }

    // single-wave block: shuffle reduce + one atomic. No LDS, no barriers.
#pragma unroll
    for (int o = 32; o > 0; o >>= 1)
        lsum += __shfl_down(lsum, o, 64);
    if (lane == 0) atomicAdd(out, lsum * SCALE);
}

extern "C" void kernel_launch(void* const* d_in, const int* in_sizes, int n_in,
                              void* d_out, int out_size, void* d_ws, size_t ws_size,
                              hipStream_t stream) {
    const float* img1 = (const float*)d_in[0];
    const float* img2 = (const float*)d_in[1];
    const float* fimg = (const float*)d_in[2];
    float* out = (float*)d_out;

    hipMemsetAsync(out, 0, sizeof(float), stream);  // d_out re-poisoned each call

    dim3 grid(2, H / SEG, BATCH);   // (2, 64, 32) = 4096 single-wave blocks
    ncc_loss_kernel<<<grid, dim3(TPB), 0, stream>>>(img1, img2, fimg, out);
}